// Round 12
// baseline (219.862 us; speedup 1.0000x reference)
//
#include <hip/hip_runtime.h>
#include <hip/hip_bf16.h>
#include <math.h>
#include <stdint.h>

#define BATCH   4
#define SEQ     2048
#define DMODEL  512
#define NHEADS  8
#define HDIM    64
#define QKV_N   (3*DMODEL)   // 1536

typedef short bf8  __attribute__((ext_vector_type(8)));   // 8 bf16 (4 VGPRs)
typedef float f32x4 __attribute__((ext_vector_type(4)));  // 4 fp32 acc

#define MFMA16(a,b,c) __builtin_amdgcn_mfma_f32_16x16x32_bf16((a),(b),(c),0,0,0)

__device__ inline unsigned short f2bf(float f){      // RNE fp32->bf16
  unsigned int u = __float_as_uint(f);
  u += 0x7FFFu + ((u >> 16) & 1u);
  return (unsigned short)(u >> 16);
}

__device__ inline unsigned int pack_bf2(float a, float b){  // v_cvt_pk_bf16_f32
  __hip_bfloat162 h = __float22bfloat162_rn(make_float2(a, b));
  return *reinterpret_cast<unsigned int*>(&h);
}

// raw v_exp_f32: computes 2^x (Q is pre-scaled by 0.125*log2(e) upstream)
__device__ __forceinline__ float exp2_hw(float x){
#if defined(__has_builtin)
#if __has_builtin(__builtin_amdgcn_exp2f)
  return __builtin_amdgcn_exp2f(x);
#else
  float r; asm("v_exp_f32 %0, %1" : "=v"(r) : "v"(x)); return r;
#endif
#else
  float r; asm("v_exp_f32 %0, %1" : "=v"(r) : "v"(x)); return r;
#endif
}

// ---------------------------------------------------------------------------
// Fused prepass: cast x -> bf16 (0..2047), transpose+cast W_qkv (2048..2239),
// transpose+cast W_out (2240..2303), per-batch valid-position compaction scan
// in VIRTUAL space (2304..2307), zero Ob (2308..2819).
// ---------------------------------------------------------------------------
__global__ __launch_bounds__(256) void prep(
    const float* __restrict__ x, const float* __restrict__ Wqkv,
    const float* __restrict__ Wout, const int* __restrict__ pmask,
    unsigned short* __restrict__ Xh, unsigned short* __restrict__ WqkvT,
    unsigned short* __restrict__ WoutT, int* __restrict__ Idx,
    int* __restrict__ Cnt, unsigned short* __restrict__ Ob)
{
  __shared__ unsigned short Ts[64][72];
  __shared__ int ps[256];
  __shared__ int tot;
  const int t = threadIdx.x;
  const int bx = blockIdx.x;
  if (bx < 2048) {
    const int i = bx*256 + t;
    const float4 a = reinterpret_cast<const float4*>(x)[2*i];
    const float4 b = reinterpret_cast<const float4*>(x)[2*i+1];
    uint4 o; unsigned short* us = reinterpret_cast<unsigned short*>(&o);
    us[0]=f2bf(a.x); us[1]=f2bf(a.y); us[2]=f2bf(a.z); us[3]=f2bf(a.w);
    us[4]=f2bf(b.x); us[5]=f2bf(b.y); us[6]=f2bf(b.z); us[7]=f2bf(b.w);
    reinterpret_cast<uint4*>(Xh)[i] = o;
    return;
  }
  if (bx >= 2308) {                                  // zero Ob (8 MB)
    const int g = (bx - 2308)*256 + t;
    uint4 z = {0u,0u,0u,0u};
    uint4* p = reinterpret_cast<uint4*>(Ob) + (size_t)g*4;
    p[0]=z; p[1]=z; p[2]=z; p[3]=z;
    return;
  }
  if (bx >= 2304) {                                  // mask compaction scan
    const int b = bx - 2304;
    const int* mb = pmask + b*SEQ;
    int loc[8]; int c = 0; const int base = t*8;
#pragma unroll
    for (int j=0;j<8;++j){ const int v = (mb[base+j] != 0); loc[j]=v; c+=v; }
    ps[t] = c; __syncthreads();
    for (int off=1; off<256; off<<=1){               // Hillis-Steele inclusive
      const int v = (t>=off) ? ps[t-off] : 0;
      __syncthreads(); ps[t] += v; __syncthreads();
    }
    int excl = ps[t] - c;
#pragma unroll
    for (int j=0;j<8;++j) if (loc[j]) Idx[b*SEQ + (excl++)] = base + j;
    if (t == 255){ Cnt[b] = ps[255]; tot = ps[255]; }
    __syncthreads();
    for (int k = tot + t; k < SEQ; k += 256) Idx[b*SEQ + k] = 0;
    return;
  }
  const float* in; unsigned short* out; int R, C, gx, gy;
  if (bx < 2048 + 192) {
    const int bid = bx - 2048;
    gx = bid % 24; gy = bid / 24; in = Wqkv; out = WqkvT; R = DMODEL; C = QKV_N;
  } else {
    const int bid = bx - 2240;
    gx = bid % 8;  gy = bid / 8;  in = Wout; out = WoutT; R = DMODEL; C = DMODEL;
  }
  const int r0 = gy<<6, c0 = gx<<6;
  const int rr = t>>2, cs = (t&3)<<4;
#pragma unroll
  for (int p=0;p<4;++p){
    float4 v = *reinterpret_cast<const float4*>(in + (size_t)(r0+rr)*C + c0 + cs + p*4);
    Ts[rr][cs+p*4+0]=f2bf(v.x); Ts[rr][cs+p*4+1]=f2bf(v.y);
    Ts[rr][cs+p*4+2]=f2bf(v.z); Ts[rr][cs+p*4+3]=f2bf(v.w);
  }
  __syncthreads();
  const int cc = t>>2, rs = (t&3)<<4;
#pragma unroll
  for (int p=0;p<4;++p){
    ushort4 o;
    o.x = Ts[rs+p*4+0][cc]; o.y = Ts[rs+p*4+1][cc];
    o.z = Ts[rs+p*4+2][cc]; o.w = Ts[rs+p*4+3][cc];
    *reinterpret_cast<ushort4*>(out + (size_t)(c0+cc)*R + r0 + rs + p*4) = o;
  }
}

// ---------------------------------------------------------------------------
// MFMA GEMM A v2: QKV = Xh @ WqkvT^T -> natural [8192][1536].
// Reg-prefetch staging (loads for k+1 fly during compute of k) + PADDED LDS
// ([128][72]: A-frag reads conflict-free) + rho-permuted B rows (B-frag
// reads become stride-1-in-lane -> conflict-free; read returns the same
// global row as before, epilogue unchanged). Was: gload_lds into unpadded
// [128][64] -> 16-way conflicts (7.86M/dispatch) + serial stage-drain.
// LDS 36 KB, ~120 VGPR -> 4 blocks/CU (was 3).
// ---------------------------------------------------------------------------
__global__ __launch_bounds__(256) void gemm_qkv_mfma(
    const unsigned short* __restrict__ A, const unsigned short* __restrict__ Bt,
    unsigned short* __restrict__ QKV)
{
  __shared__ unsigned short As[128][72];
  __shared__ unsigned short Bs[128][72];
  const int t = threadIdx.x;
  const int w = t>>6, lane = t&63, quad = lane>>4, l15 = lane&15;
  const int wr = (w>>1)<<6, wc = (w&1)<<6;
  const int linear = blockIdx.y*12 + blockIdx.x;     // 768 blocks
  const int swz = (linear & 7)*96 + (linear >> 3);   // bijective (768%8==0)
  const int m0 = (swz/12)<<7, n0 = (swz%12)<<7;
  const int row = t>>3, seg = t&7;
  const unsigned short* Agp = A  + (size_t)(m0+row)*DMODEL + seg*8;
  const unsigned short* Bgp = Bt + (size_t)(n0+row)*DMODEL + seg*8;
  int wrB[4];
#pragma unroll
  for (int p=0;p<4;++p){
    const int m = row + (p<<5);                      // 0..127
    wrB[p] = (m & 64) | ((m & 3) << 4) | ((m & 63) >> 2);   // rho-permute
  }
  f32x4 acc[4][4];
#pragma unroll
  for (int i=0;i<4;++i)
#pragma unroll
    for (int j=0;j<4;++j) acc[i][j] = (f32x4){0.f,0.f,0.f,0.f};

  uint4 ga[4], gb[4];
#pragma unroll
  for (int p=0;p<4;++p){                             // prologue: k0 = 0
    ga[p] = *reinterpret_cast<const uint4*>(Agp + (size_t)p*32*DMODEL);
    gb[p] = *reinterpret_cast<const uint4*>(Bgp + (size_t)p*32*DMODEL);
  }
  for (int k0=0;k0<DMODEL;k0+=64){
#pragma unroll
    for (int p=0;p<4;++p){
      *reinterpret_cast<uint4*>(&As[row+(p<<5)][seg*8]) = ga[p];
      *reinterpret_cast<uint4*>(&Bs[wrB[p]][seg*8])     = gb[p];
    }
    __syncthreads();                                 // tiles visible
    if (k0 + 64 < DMODEL){                           // prefetch k0+64
#pragma unroll
      for (int p=0;p<4;++p){
        ga[p] = *reinterpret_cast<const uint4*>(Agp + (size_t)p*32*DMODEL + k0 + 64);
        gb[p] = *reinterpret_cast<const uint4*>(Bgp + (size_t)p*32*DMODEL + k0 + 64);
      }
    }
#pragma unroll
    for (int ks=0;ks<2;++ks){
      bf8 af[4], bfr[4];
#pragma unroll
      for (int mi=0;mi<4;++mi)
        af[mi]  = *reinterpret_cast<const bf8*>(&As[wr+mi*16+l15][ks*32+quad*8]);
#pragma unroll
      for (int nj=0;nj<4;++nj)                       // rho-read: global row wc+4*l15+nj
        bfr[nj] = *reinterpret_cast<const bf8*>(&Bs[wc+(nj<<4)+l15][ks*32+quad*8]);
#pragma unroll
      for (int mi=0;mi<4;++mi)
#pragma unroll
        for (int nj=0;nj<4;++nj) acc[mi][nj] = MFMA16(af[mi], bfr[nj], acc[mi][nj]);
    }
    __syncthreads();                                 // reads done; drains prefetch
  }
  const int cbase = n0 + wc + (l15<<2);
  bool isq[4];
#pragma unroll
  for (int nj=0;nj<4;++nj) isq[nj] = ((cbase+nj) % 192) < 64;
#pragma unroll
  for (int mi=0;mi<4;++mi)
#pragma unroll
    for (int i=0;i<4;++i){
      const int m = m0 + wr + mi*16 + quad*4 + i;
      unsigned long long pk = 0;
#pragma unroll
      for (int nj=0;nj<4;++nj){
        float v = acc[mi][nj][i];
        if (isq[nj]) v *= 0.18033688f;               // 0.125 * log2(e)
        pk |= (unsigned long long)f2bf(v) << (16*nj);
      }
      *reinterpret_cast<unsigned long long*>(QKV + (size_t)m*QKV_N + cbase) = pk;
    }
}

// ---------------------------------------------------------------------------
// V^T builder (compacted in VIRTUAL space): VT[bh][d][j] = V of virtual
// position Idx[b][j]. Tiles beyond ceil64(cnt[b]) exit (never read).
// ---------------------------------------------------------------------------
__global__ __launch_bounds__(256) void v_transpose(
    const unsigned short* __restrict__ QKV, const int* __restrict__ Idx,
    const int* __restrict__ Cnt, unsigned short* __restrict__ VT)
{
  __shared__ unsigned short Td[64][76];
  const int t = threadIdx.x;
  const int bh = blockIdx.y, b = bh>>3, hp = bh&7;
  const int s0 = blockIdx.x<<6;
  if (s0 >= ((Cnt[b] + 63) & ~63)) return;           // dead tile
  const size_t rbase = (size_t)(b*SEQ + hp*256);
  const int sr = t>>2, db = (t&3)<<4;
  const int s = Idx[b*SEQ + s0 + sr];                // gather source key
  const unsigned short* vp =
      QKV + (rbase + (s>>3))*QKV_N + (s&7)*192 + 128 + db;
  uint4 a = *reinterpret_cast<const uint4*>(vp);
  uint4 c = *reinterpret_cast<const uint4*>(vp + 8);
  const unsigned short* ua = reinterpret_cast<const unsigned short*>(&a);
  const unsigned short* uc = reinterpret_cast<const unsigned short*>(&c);
#pragma unroll
  for (int j=0;j<8;++j) Td[db+j][sr]   = ua[j];
#pragma unroll
  for (int j=0;j<8;++j) Td[db+8+j][sr] = uc[j];
  __syncthreads();
  const int L = t&15, d0 = t>>4;
  unsigned short* Op = VT + (size_t)bh*HDIM*SEQ + s0 + (L<<2);
#pragma unroll
  for (int cc=0;cc<4;++cc){
    const int d = d0 + (cc<<4);
    *reinterpret_cast<unsigned long long*>(Op + (size_t)d*SEQ) =
        *reinterpret_cast<const unsigned long long*>(&Td[d][L<<2]);
  }
}

// ---------------------------------------------------------------------------
// MFMA flash attention v14: q-compaction on the 8-wave 128q/block geometry.
// Q/K gathered via Idx; VT pre-compacted; tail key mask (pos < cnt);
// epilogue scatters to ORIGINAL positions (Ob pre-zeroed).
// ---------------------------------------------------------------------------
__global__ __launch_bounds__(512, 4) void attn_mfma(
    const unsigned short* __restrict__ QKV, const unsigned short* __restrict__ VT,
    const int* __restrict__ Idx, const int* __restrict__ Cnt,
    unsigned short* __restrict__ O)
{
  __shared__ unsigned short Ks[2][64][72];   // rho-permuted K tiles [row][d]
  __shared__ unsigned short Vs[2][64][72];   // V^T tiles [d][key]
  __shared__ unsigned short Pl[8][16][72];   // wave-private P [q][key]
  const int t = threadIdx.x;
  const int w = t>>6, lane = t&63, quad = lane>>4, l15 = lane&15;
  const int linear = blockIdx.y*16 + blockIdx.x;     // 512 blocks
  const int swz = (linear & 7)*64 + (linear >> 3);   // bijective (512%8==0)
  const int bh = swz >> 4, b = bh>>3, hp = bh&7;
  const int q0 = (swz & 15) << 7;            // 128 queries per block
  const int kcnt = Cnt[b];
  const int kend = (kcnt + 63) & ~63;                // compacted tile span
  if (q0 >= kend) return;                            // dead q-tile (block-uniform)
  const int qs = q0 + (w<<4);                // 16 per wave
  const int* Idxb = Idx + b*SEQ;
  const f32x4 Z4 = {0.f,0.f,0.f,0.f};

  const size_t rbase = (size_t)(b*SEQ + hp*256);   // qkv row base for this bh
  bf8 qf[2];
  {
    const int sq = Idxb[qs + l15];                   // virtual-space gather
    const unsigned short* qp =
        QKV + (rbase + (sq>>3))*QKV_N + (sq&7)*192 + (quad<<3);
    qf[0] = *reinterpret_cast<const bf8*>(qp);
    qf[1] = *reinterpret_cast<const bf8*>(qp + 32);
  }
  const unsigned short* Vg = VT + (size_t)bh*HDIM*SEQ;

  bf8 ones;
#pragma unroll
  for (int j=0;j<8;++j) ones[j] = (short)0x3F80;    // bf16 1.0

  const int srow = t>>3, sc8 = (t&7)<<3;             // staging: key row, col
  const int krow = ((srow&3)<<4) + (srow>>2);        // rho(srow)

  f32x4 of[4]; f32x4 lsv = Z4;
#pragma unroll
  for (int i=0;i<4;++i) of[i]=Z4;

  uint4 gk0, gv0;
  {                                                  // load tile 0 (gathered)
    const int s = Idxb[srow];
    const unsigned short* kp =
        QKV + (rbase + (s>>3))*QKV_N + (s&7)*192 + 64 + sc8;
    gk0 = *reinterpret_cast<const uint4*>(kp);
    gv0 = *reinterpret_cast<const uint4*>(Vg + (size_t)srow*SEQ + sc8);
  }
  // write buf0 (waits on tile-0 loads), then issue tile-1 loads
  *reinterpret_cast<uint4*>(&Ks[0][krow][sc8]) = gk0;
  *reinterpret_cast<uint4*>(&Vs[0][srow][sc8]) = gv0;
  {
    const int s = Idxb[64 + srow];
    const unsigned short* kp =
        QKV + (rbase + (s>>3))*QKV_N + (s&7)*192 + 64 + sc8;
    gk0 = *reinterpret_cast<const uint4*>(kp);
    gv0 = *reinterpret_cast<const uint4*>(Vg + (size_t)srow*SEQ + 64 + sc8);
  }
  __syncthreads();                                   // buf0 visible

  auto iter = [&](unsigned short (&KSC)[64][72], unsigned short (&VSC)[64][72],
                  unsigned short (&KSN)[64][72], unsigned short (&VSN)[64][72],
                  int kt) {
    if (kt + 64 < kend){                             // stage tile t+1 -> NXT
      *reinterpret_cast<uint4*>(&KSN[krow][sc8]) = gk0;
      *reinterpret_cast<uint4*>(&VSN[srow][sc8]) = gv0;
    }
    if (kt + 128 < kend){                            // issue loads tile t+2
      const int s = Idxb[kt + 128 + srow];
      const unsigned short* kp =
          QKV + (rbase + (s>>3))*QKV_N + (s&7)*192 + 64 + sc8;
      gk0 = *reinterpret_cast<const uint4*>(kp);
      gv0 = *reinterpret_cast<const uint4*>(
          Vg + (size_t)srow*SEQ + (kt + 128) + sc8);
    }

    bf8 kf[4][2];
#pragma unroll
    for (int nf=0;nf<4;++nf){
      kf[nf][0] = *reinterpret_cast<const bf8*>(&KSC[nf*16+l15][quad<<3]);
      kf[nf][1] = *reinterpret_cast<const bf8*>(&KSC[nf*16+l15][32+(quad<<3)]);
    }

    f32x4 sc[4];
    __builtin_amdgcn_s_setprio(1);
#pragma unroll
    for (int nf=0;nf<4;++nf){
      f32x4 s = MFMA16(qf[0], kf[nf][0], Z4);
      sc[nf] = MFMA16(qf[1], kf[nf][1], s);
    }
    __builtin_amdgcn_s_setprio(0);
    const int kbase = kt + (l15<<2);
    float pv[4][4];
#pragma unroll
    for (int nf=0;nf<4;++nf){
      const bool on = (kbase + nf) < kcnt;           // tail-tile mask only
#pragma unroll
      for (int i=0;i<4;++i)
        pv[nf][i] = on ? exp2_hw(sc[nf][i]) : 0.f;   // Q pre-scaled 0.125*log2e
    }
#pragma unroll
    for (int i=0;i<4;++i){
      const unsigned int lo = pack_bf2(pv[0][i], pv[1][i]);
      const unsigned int hi = pack_bf2(pv[2][i], pv[3][i]);
      *reinterpret_cast<unsigned long long*>(&Pl[w][(quad<<2)+i][l15<<2]) =
          ((unsigned long long)hi<<32) | lo;
    }

    bf8 pa[2];
    pa[0] = *reinterpret_cast<const bf8*>(&Pl[w][l15][quad<<3]);
    pa[1] = *reinterpret_cast<const bf8*>(&Pl[w][l15][32+(quad<<3)]);
    __builtin_amdgcn_s_setprio(1);
    {                                                // lsum on the MFMA pipe
      f32x4 l = MFMA16(pa[0], ones, lsv);
      lsv = MFMA16(pa[1], ones, l);
    }
#pragma unroll
    for (int nf=0;nf<4;++nf){
      const bf8 v0 = *reinterpret_cast<const bf8*>(&VSC[nf*16+l15][quad<<3]);
      const bf8 v1 = *reinterpret_cast<const bf8*>(&VSC[nf*16+l15][32+(quad<<3)]);
      f32x4 o = MFMA16(pa[0], v0, of[nf]);
      of[nf] = MFMA16(pa[1], v1, o);
    }
    __builtin_amdgcn_s_setprio(0);
    __syncthreads();                                 // single barrier per tile
  };

  for (int kt=0; kt<kend; kt+=128){
    iter(Ks[0], Vs[0], Ks[1], Vs[1], kt);
    if (kt + 64 < kend)
      iter(Ks[1], Vs[1], Ks[0], Vs[0], kt+64);
  }

  // scatter valid rows to ORIGINAL positions (Ob pre-zeroed)
  unsigned short* Op = O + (size_t)bh*SEQ*HDIM;
#pragma unroll
  for (int i=0;i<4;++i){
    const int q = qs + (quad<<2) + i;                // compacted q index
    if (q < kcnt){
      const int orig = Idxb[q];
      const float l = lsv[i];
      const float inv = (l > 0.f) ? 1.f/l : 0.f;
#pragma unroll
      for (int nf=0;nf<4;++nf)
        Op[(size_t)orig*HDIM + (nf<<4) + l15] = f2bf(of[nf][i]*inv);
    }
  }
}

// ---------------------------------------------------------------------------
// MFMA GEMM C v2: out = Ob @ WoutT^T, fp32 stores. 128x64 tiles, 512 blocks.
// Same reg-prefetch + padded LDS + rho-permuted B transform as gemm_qkv
// (B rows stride-2 per lane -> rho2(m)=(m&32)|((m&1)<<4)|((m&31)>>1)).
// ---------------------------------------------------------------------------
__global__ __launch_bounds__(256) void gemm_out_mfma(
    const unsigned short* __restrict__ A, const unsigned short* __restrict__ Bt,
    float* __restrict__ Out)
{
  __shared__ unsigned short As[128][72];
  __shared__ unsigned short Bs[64][72];
  const int t = threadIdx.x;
  const int w = t>>6, lane = t&63, quad = lane>>4, l15 = lane&15;
  const int wr = (w>>1)<<6, wc = (w&1)<<5;
  const int linear = blockIdx.y*8 + blockIdx.x;      // grid (8,64) = 512
  const int swz = (linear & 7)*64 + (linear >> 3);   // bijective (512%8==0)
  const int m0 = (swz>>3)<<7, n0 = (swz&7)<<6;
  const int row = t>>3, seg = t&7;
  const unsigned short* Agp = A  + (size_t)(m0+row)*DMODEL + seg*8;
  const unsigned short* Bgp = Bt + (size_t)(n0+row)*DMODEL + seg*8;
  int wrB[2];
#pragma unroll
  for (int p=0;p<2;++p){
    const int m = row + (p<<5);                      // 0..63
    wrB[p] = (m & 32) | ((m & 1) << 4) | ((m & 31) >> 1);   // rho2-permute
  }
  f32x4 acc[4][2];
#pragma unroll
  for (int i=0;i<4;++i)
#pragma unroll
    for (int j=0;j<2;++j) acc[i][j] = (f32x4){0.f,0.f,0.f,0.f};

  uint4 ga[4], gb[2];
#pragma unroll
  for (int p=0;p<4;++p)
    ga[p] = *reinterpret_cast<const uint4*>(Agp + (size_t)p*32*DMODEL);
#pragma unroll
  for (int p=0;p<2;++p)
    gb[p] = *reinterpret_cast<const uint4*>(Bgp + (size_t)p*32*DMODEL);

  for (int k0=0;k0<DMODEL;k0+=64){
#pragma unroll
    for (int p=0;p<4;++p)
      *reinterpret_cast<uint4*>(&As[row+(p<<5)][seg*8]) = ga[p];
#pragma unroll
    for (int p=0;p<2;++p)
      *reinterpret_cast<uint4*>(&Bs[wrB[p]][seg*8]) = gb[p];
    __syncthreads();
    if (k0 + 64 < DMODEL){
#pragma unroll
      for (int p=0;p<4;++p)
        ga[p] = *reinterpret_cast<const uint4*>(Agp + (size_t)p*32*DMODEL + k0 + 64);
#pragma unroll
      for (int p=0;p<2;++p)
        gb[p] = *reinterpret_cast<const uint4*>(Bgp + (size_t)p*32*DMODEL + k0 + 64);
    }
#pragma unroll
    for (int ks=0;ks<2;++ks){
      bf8 af[4], bfr[2];
#pragma unroll
      for (int mi=0;mi<4;++mi)
        af[mi]  = *reinterpret_cast<const bf8*>(&As[wr+mi*16+l15][ks*32+quad*8]);
#pragma unroll
      for (int nj=0;nj<2;++nj)                       // rho2-read: global row wc+2*l15+nj
        bfr[nj] = *reinterpret_cast<const bf8*>(&Bs[wc+(nj<<4)+l15][ks*32+quad*8]);
#pragma unroll
      for (int mi=0;mi<4;++mi)
#pragma unroll
        for (int nj=0;nj<2;++nj) acc[mi][nj] = MFMA16(af[mi], bfr[nj], acc[mi][nj]);
    }
    __syncthreads();
  }
  const int cbase = n0 + wc + (l15<<1);
#pragma unroll
  for (int mi=0;mi<4;++mi)
#pragma unroll
    for (int i=0;i<4;++i){
      const int m = m0 + wr + mi*16 + quad*4 + i;
      const float2 o = make_float2(acc[mi][0][i], acc[mi][1][i]);
      *reinterpret_cast<float2*>(Out + (size_t)m*DMODEL + cbase) = o;
    }
}

// ---------------------------------------------------------------------------
extern "C" void kernel_launch(void* const* d_in, const int* in_sizes, int n_in,
                              void* d_out, int out_size, void* d_ws, size_t ws_size,
                              hipStream_t stream) {
  (void)in_sizes; (void)n_in; (void)out_size; (void)ws_size;
  const float* x     = (const float*)d_in[0];
  const int*   pmask = (const int*)d_in[2];
  const float* Wqkv  = (const float*)d_in[3];
  const float* Wout  = (const float*)d_in[4];
  float* out = (float*)d_out;

  const size_t per = (size_t)BATCH*NHEADS*SEQ*HDIM;     // 4,194,304
  unsigned short* Xh    = (unsigned short*)d_ws;
  unsigned short* WqkvT = Xh    + (size_t)8192*512;
  unsigned short* WoutT = WqkvT + (size_t)1536*512;
  unsigned short* QKVb  = WoutT + (size_t)512*512;
  unsigned short* VbT   = QKVb  + (size_t)8192*QKV_N;
  unsigned short* Ob    = VbT + per;
  int* Idx = (int*)(Ob + per);                          // [BATCH][SEQ]
  int* Cnt = Idx + (size_t)BATCH*SEQ;                   // [BATCH]

  prep<<<2820, 256, 0, stream>>>(x, Wqkv, Wout, pmask, Xh, WqkvT, WoutT,
                                 Idx, Cnt, Ob);
  gemm_qkv_mfma<<<dim3(QKV_N/128, 8192/128), 256, 0, stream>>>(Xh, WqkvT, QKVb);
  v_transpose<<<dim3(SEQ/64, BATCH*NHEADS), 256, 0, stream>>>(
      QKVb, Idx, Cnt, VbT);
  attn_mfma<<<dim3(SEQ/128, BATCH*NHEADS), 512, 0, stream>>>(
      QKVb, VbT, Idx, Cnt, Ob);
  gemm_out_mfma<<<dim3(DMODEL/64, 8192/128), 256, 0, stream>>>(Ob, WoutT, out);
}

// Round 14
// 153.236 us; speedup vs baseline: 1.4348x; 1.4348x over previous
//
#include <hip/hip_runtime.h>
#include <hip/hip_bf16.h>
#include <math.h>
#include <stdint.h>

#define BATCH   4
#define SEQ     2048
#define DMODEL  512
#define NHEADS  8
#define HDIM    64
#define QKV_N   (3*DMODEL)   // 1536

typedef short bf8  __attribute__((ext_vector_type(8)));   // 8 bf16 (4 VGPRs)
typedef float f32x4 __attribute__((ext_vector_type(4)));  // 4 fp32 acc

#define MFMA16(a,b,c) __builtin_amdgcn_mfma_f32_16x16x32_bf16((a),(b),(c),0,0,0)

__device__ inline unsigned short f2bf(float f){      // RNE fp32->bf16
  unsigned int u = __float_as_uint(f);
  u += 0x7FFFu + ((u >> 16) & 1u);
  return (unsigned short)(u >> 16);
}

__device__ inline unsigned int pack_bf2(float a, float b){  // v_cvt_pk_bf16_f32
  __hip_bfloat162 h = __float22bfloat162_rn(make_float2(a, b));
  return *reinterpret_cast<unsigned int*>(&h);
}

// raw v_exp_f32: computes 2^x (Q is pre-scaled by 0.125*log2(e) upstream)
__device__ __forceinline__ float exp2_hw(float x){
#if defined(__has_builtin)
#if __has_builtin(__builtin_amdgcn_exp2f)
  return __builtin_amdgcn_exp2f(x);
#else
  float r; asm("v_exp_f32 %0, %1" : "=v"(r) : "v"(x)); return r;
#endif
#else
  float r; asm("v_exp_f32 %0, %1" : "=v"(r) : "v"(x)); return r;
#endif
}

// global -> LDS direct DMA, 16 B per lane. LDS dest = wave-uniform base +
// lane*16 (LDS stays LINEAR; swizzles are applied on the per-lane GLOBAL
// source address + matching read offset — rule #21 both-sides involution).
__device__ __forceinline__ void gload_lds16(const unsigned short* g,
                                            unsigned short* l){
  __builtin_amdgcn_global_load_lds(
      (const __attribute__((address_space(1))) unsigned int*)g,
      (__attribute__((address_space(3))) unsigned int*)l,
      16, 0, 0);
}

// ---------------------------------------------------------------------------
// Fused prepass: cast x -> bf16 (0..2047), transpose+cast W_qkv (2048..2239),
// transpose+cast W_out (2240..2303), per-batch valid-position compaction scan
// in VIRTUAL space (2304..2307), zero Ob (2308..2819).
// ---------------------------------------------------------------------------
__global__ __launch_bounds__(256) void prep(
    const float* __restrict__ x, const float* __restrict__ Wqkv,
    const float* __restrict__ Wout, const int* __restrict__ pmask,
    unsigned short* __restrict__ Xh, unsigned short* __restrict__ WqkvT,
    unsigned short* __restrict__ WoutT, int* __restrict__ Idx,
    int* __restrict__ Cnt, unsigned short* __restrict__ Ob)
{
  __shared__ unsigned short Ts[64][72];
  __shared__ int ps[256];
  __shared__ int tot;
  const int t = threadIdx.x;
  const int bx = blockIdx.x;
  if (bx < 2048) {
    const int i = bx*256 + t;
    const float4 a = reinterpret_cast<const float4*>(x)[2*i];
    const float4 b = reinterpret_cast<const float4*>(x)[2*i+1];
    uint4 o; unsigned short* us = reinterpret_cast<unsigned short*>(&o);
    us[0]=f2bf(a.x); us[1]=f2bf(a.y); us[2]=f2bf(a.z); us[3]=f2bf(a.w);
    us[4]=f2bf(b.x); us[5]=f2bf(b.y); us[6]=f2bf(b.z); us[7]=f2bf(b.w);
    reinterpret_cast<uint4*>(Xh)[i] = o;
    return;
  }
  if (bx >= 2308) {                                  // zero Ob (8 MB)
    const int g = (bx - 2308)*256 + t;
    uint4 z = {0u,0u,0u,0u};
    uint4* p = reinterpret_cast<uint4*>(Ob) + (size_t)g*4;
    p[0]=z; p[1]=z; p[2]=z; p[3]=z;
    return;
  }
  if (bx >= 2304) {                                  // mask compaction scan
    const int b = bx - 2304;
    const int* mb = pmask + b*SEQ;
    int loc[8]; int c = 0; const int base = t*8;
#pragma unroll
    for (int j=0;j<8;++j){ const int v = (mb[base+j] != 0); loc[j]=v; c+=v; }
    ps[t] = c; __syncthreads();
    for (int off=1; off<256; off<<=1){               // Hillis-Steele inclusive
      const int v = (t>=off) ? ps[t-off] : 0;
      __syncthreads(); ps[t] += v; __syncthreads();
    }
    int excl = ps[t] - c;
#pragma unroll
    for (int j=0;j<8;++j) if (loc[j]) Idx[b*SEQ + (excl++)] = base + j;
    if (t == 255){ Cnt[b] = ps[255]; tot = ps[255]; }
    __syncthreads();
    for (int k = tot + t; k < SEQ; k += 256) Idx[b*SEQ + k] = 0;
    return;
  }
  const float* in; unsigned short* out; int R, C, gx, gy;
  if (bx < 2048 + 192) {
    const int bid = bx - 2048;
    gx = bid % 24; gy = bid / 24; in = Wqkv; out = WqkvT; R = DMODEL; C = QKV_N;
  } else {
    const int bid = bx - 2240;
    gx = bid % 8;  gy = bid / 8;  in = Wout; out = WoutT; R = DMODEL; C = DMODEL;
  }
  const int r0 = gy<<6, c0 = gx<<6;
  const int rr = t>>2, cs = (t&3)<<4;
#pragma unroll
  for (int p=0;p<4;++p){
    float4 v = *reinterpret_cast<const float4*>(in + (size_t)(r0+rr)*C + c0 + cs + p*4);
    Ts[rr][cs+p*4+0]=f2bf(v.x); Ts[rr][cs+p*4+1]=f2bf(v.y);
    Ts[rr][cs+p*4+2]=f2bf(v.z); Ts[rr][cs+p*4+3]=f2bf(v.w);
  }
  __syncthreads();
  const int cc = t>>2, rs = (t&3)<<4;
#pragma unroll
  for (int p=0;p<4;++p){
    ushort4 o;
    o.x = Ts[rs+p*4+0][cc]; o.y = Ts[rs+p*4+1][cc];
    o.z = Ts[rs+p*4+2][cc]; o.w = Ts[rs+p*4+3][cc];
    *reinterpret_cast<ushort4*>(out + (size_t)(c0+cc)*R + r0 + rs + p*4) = o;
  }
}

// ---------------------------------------------------------------------------
// MFMA GEMM A (m97 structure + chunk-swizzle): QKV = Xh @ WqkvT^T.
// gload_lds staging into LINEAR unpadded [128][64] tiles (zero VGPR cost —
// round-12's reg-prefetch spilled to scratch, +135 MB writes). Bank fix via
// pre-swizzled GLOBAL chunks: row r's chunk c lives at position c^f(r)
// (A: f=r&7, B: f=(r>>2)&7) and reads apply the same XOR -> exactly 8
// lanes/bank-group per b128 (hardware minimum, was 16).
// ---------------------------------------------------------------------------
__global__ __launch_bounds__(256) void gemm_qkv_mfma(
    const unsigned short* __restrict__ A, const unsigned short* __restrict__ Bt,
    unsigned short* __restrict__ QKV)
{
  __shared__ unsigned short As[128][64];
  __shared__ unsigned short Bs[128][64];
  const int t = threadIdx.x;
  const int w = t>>6, lane = t&63, quad = lane>>4, l15 = lane&15;
  const int wr = (w>>1)<<6, wc = (w&1)<<6;
  const int linear = blockIdx.y*12 + blockIdx.x;     // 768 blocks
  const int swz = (linear & 7)*96 + (linear >> 3);   // bijective (768%8==0)
  const int m0 = (swz/12)<<7, n0 = (swz%12)<<7;
  const int row = t>>3, seg = t&7;
  const int sa = (seg ^ (row & 7)) << 3;             // A source chunk-swizzle
  const int sb = (seg ^ ((row >> 2) & 7)) << 3;      // B source chunk-swizzle
  const unsigned short* Agp = A  + (size_t)(m0+row)*DMODEL + sa;
  const unsigned short* Bgp = Bt + (size_t)(n0+row)*DMODEL + sb;
  f32x4 acc[4][4];
#pragma unroll
  for (int i=0;i<4;++i)
#pragma unroll
    for (int j=0;j<4;++j) acc[i][j] = (f32x4){0.f,0.f,0.f,0.f};

  for (int k0=0;k0<DMODEL;k0+=64){
    __syncthreads();
#pragma unroll
    for (int p=0;p<4;++p){
      gload_lds16(Agp + (size_t)p*32*DMODEL + k0, &As[(w<<3)+(p<<5)][0]);
      gload_lds16(Bgp + (size_t)p*32*DMODEL + k0, &Bs[(w<<3)+(p<<5)][0]);
    }
    __syncthreads();
#pragma unroll
    for (int ks=0;ks<2;++ks){
      const int co = (((ks<<2)|quad) ^ (l15&7)) << 3;  // swizzled read offset
      bf8 af[4], bfr[4];
#pragma unroll
      for (int mi=0;mi<4;++mi)
        af[mi]  = *reinterpret_cast<const bf8*>(&As[wr+mi*16+l15][co]);
#pragma unroll
      for (int nj=0;nj<4;++nj)
        bfr[nj] = *reinterpret_cast<const bf8*>(&Bs[wc+(l15<<2)+nj][co]);
#pragma unroll
      for (int mi=0;mi<4;++mi)
#pragma unroll
        for (int nj=0;nj<4;++nj) acc[mi][nj] = MFMA16(af[mi], bfr[nj], acc[mi][nj]);
    }
  }
  const int cbase = n0 + wc + (l15<<2);
  bool isq[4];
#pragma unroll
  for (int nj=0;nj<4;++nj) isq[nj] = ((cbase+nj) % 192) < 64;
#pragma unroll
  for (int mi=0;mi<4;++mi)
#pragma unroll
    for (int i=0;i<4;++i){
      const int m = m0 + wr + mi*16 + quad*4 + i;
      unsigned long long pk = 0;
#pragma unroll
      for (int nj=0;nj<4;++nj){
        float v = acc[mi][nj][i];
        if (isq[nj]) v *= 0.18033688f;               // 0.125 * log2(e)
        pk |= (unsigned long long)f2bf(v) << (16*nj);
      }
      *reinterpret_cast<unsigned long long*>(QKV + (size_t)m*QKV_N + cbase) = pk;
    }
}

// ---------------------------------------------------------------------------
// V^T builder (compacted in VIRTUAL space): VT[bh][d][j] = V of virtual
// position Idx[b][j]. Tiles beyond ceil64(cnt[b]) exit (never read).
// ---------------------------------------------------------------------------
__global__ __launch_bounds__(256) void v_transpose(
    const unsigned short* __restrict__ QKV, const int* __restrict__ Idx,
    const int* __restrict__ Cnt, unsigned short* __restrict__ VT)
{
  __shared__ unsigned short Td[64][76];
  const int t = threadIdx.x;
  const int bh = blockIdx.y, b = bh>>3, hp = bh&7;
  const int s0 = blockIdx.x<<6;
  if (s0 >= ((Cnt[b] + 63) & ~63)) return;           // dead tile
  const size_t rbase = (size_t)(b*SEQ + hp*256);
  const int sr = t>>2, db = (t&3)<<4;
  const int s = Idx[b*SEQ + s0 + sr];                // gather source key
  const unsigned short* vp =
      QKV + (rbase + (s>>3))*QKV_N + (s&7)*192 + 128 + db;
  uint4 a = *reinterpret_cast<const uint4*>(vp);
  uint4 c = *reinterpret_cast<const uint4*>(vp + 8);
  const unsigned short* ua = reinterpret_cast<const unsigned short*>(&a);
  const unsigned short* uc = reinterpret_cast<const unsigned short*>(&c);
#pragma unroll
  for (int j=0;j<8;++j) Td[db+j][sr]   = ua[j];
#pragma unroll
  for (int j=0;j<8;++j) Td[db+8+j][sr] = uc[j];
  __syncthreads();
  const int L = t&15, d0 = t>>4;
  unsigned short* Op = VT + (size_t)bh*HDIM*SEQ + s0 + (L<<2);
#pragma unroll
  for (int cc=0;cc<4;++cc){
    const int d = d0 + (cc<<4);
    *reinterpret_cast<unsigned long long*>(Op + (size_t)d*SEQ) =
        *reinterpret_cast<const unsigned long long*>(&Td[d][L<<2]);
  }
}

// ---------------------------------------------------------------------------
// MFMA flash attention v14: q-compaction on the 8-wave 128q/block geometry.
// Q/K gathered via Idx; VT pre-compacted; tail key mask (pos < cnt);
// epilogue scatters to ORIGINAL positions (Ob pre-zeroed).
// ---------------------------------------------------------------------------
__global__ __launch_bounds__(512, 4) void attn_mfma(
    const unsigned short* __restrict__ QKV, const unsigned short* __restrict__ VT,
    const int* __restrict__ Idx, const int* __restrict__ Cnt,
    unsigned short* __restrict__ O)
{
  __shared__ unsigned short Ks[2][64][72];   // rho-permuted K tiles [row][d]
  __shared__ unsigned short Vs[2][64][72];   // V^T tiles [d][key]
  __shared__ unsigned short Pl[8][16][72];   // wave-private P [q][key]
  const int t = threadIdx.x;
  const int w = t>>6, lane = t&63, quad = lane>>4, l15 = lane&15;
  const int linear = blockIdx.y*16 + blockIdx.x;     // 512 blocks
  const int swz = (linear & 7)*64 + (linear >> 3);   // bijective (512%8==0)
  const int bh = swz >> 4, b = bh>>3, hp = bh&7;
  const int q0 = (swz & 15) << 7;            // 128 queries per block
  const int kcnt = Cnt[b];
  const int kend = (kcnt + 63) & ~63;                // compacted tile span
  if (q0 >= kend) return;                            // dead q-tile (block-uniform)
  const int qs = q0 + (w<<4);                // 16 per wave
  const int* Idxb = Idx + b*SEQ;
  const f32x4 Z4 = {0.f,0.f,0.f,0.f};

  const size_t rbase = (size_t)(b*SEQ + hp*256);   // qkv row base for this bh
  bf8 qf[2];
  {
    const int sq = Idxb[qs + l15];                   // virtual-space gather
    const unsigned short* qp =
        QKV + (rbase + (sq>>3))*QKV_N + (sq&7)*192 + (quad<<3);
    qf[0] = *reinterpret_cast<const bf8*>(qp);
    qf[1] = *reinterpret_cast<const bf8*>(qp + 32);
  }
  const unsigned short* Vg = VT + (size_t)bh*HDIM*SEQ;

  bf8 ones;
#pragma unroll
  for (int j=0;j<8;++j) ones[j] = (short)0x3F80;    // bf16 1.0

  const int srow = t>>3, sc8 = (t&7)<<3;             // staging: key row, col
  const int krow = ((srow&3)<<4) + (srow>>2);        // rho(srow)

  f32x4 of[4]; f32x4 lsv = Z4;
#pragma unroll
  for (int i=0;i<4;++i) of[i]=Z4;

  uint4 gk0, gv0;
  {                                                  // load tile 0 (gathered)
    const int s = Idxb[srow];
    const unsigned short* kp =
        QKV + (rbase + (s>>3))*QKV_N + (s&7)*192 + 64 + sc8;
    gk0 = *reinterpret_cast<const uint4*>(kp);
    gv0 = *reinterpret_cast<const uint4*>(Vg + (size_t)srow*SEQ + sc8);
  }
  // write buf0 (waits on tile-0 loads), then issue tile-1 loads
  *reinterpret_cast<uint4*>(&Ks[0][krow][sc8]) = gk0;
  *reinterpret_cast<uint4*>(&Vs[0][srow][sc8]) = gv0;
  {
    const int s = Idxb[64 + srow];
    const unsigned short* kp =
        QKV + (rbase + (s>>3))*QKV_N + (s&7)*192 + 64 + sc8;
    gk0 = *reinterpret_cast<const uint4*>(kp);
    gv0 = *reinterpret_cast<const uint4*>(Vg + (size_t)srow*SEQ + 64 + sc8);
  }
  __syncthreads();                                   // buf0 visible

  auto iter = [&](unsigned short (&KSC)[64][72], unsigned short (&VSC)[64][72],
                  unsigned short (&KSN)[64][72], unsigned short (&VSN)[64][72],
                  int kt) {
    if (kt + 64 < kend){                             // stage tile t+1 -> NXT
      *reinterpret_cast<uint4*>(&KSN[krow][sc8]) = gk0;
      *reinterpret_cast<uint4*>(&VSN[srow][sc8]) = gv0;
    }
    if (kt + 128 < kend){                            // issue loads tile t+2
      const int s = Idxb[kt + 128 + srow];
      const unsigned short* kp =
          QKV + (rbase + (s>>3))*QKV_N + (s&7)*192 + 64 + sc8;
      gk0 = *reinterpret_cast<const uint4*>(kp);
      gv0 = *reinterpret_cast<const uint4*>(
          Vg + (size_t)srow*SEQ + (kt + 128) + sc8);
    }

    bf8 kf[4][2];
#pragma unroll
    for (int nf=0;nf<4;++nf){
      kf[nf][0] = *reinterpret_cast<const bf8*>(&KSC[nf*16+l15][quad<<3]);
      kf[nf][1] = *reinterpret_cast<const bf8*>(&KSC[nf*16+l15][32+(quad<<3)]);
    }

    f32x4 sc[4];
    __builtin_amdgcn_s_setprio(1);
#pragma unroll
    for (int nf=0;nf<4;++nf){
      f32x4 s = MFMA16(qf[0], kf[nf][0], Z4);
      sc[nf] = MFMA16(qf[1], kf[nf][1], s);
    }
    __builtin_amdgcn_s_setprio(0);
    const int kbase = kt + (l15<<2);
    float pv[4][4];
#pragma unroll
    for (int nf=0;nf<4;++nf){
      const bool on = (kbase + nf) < kcnt;           // tail-tile mask only
#pragma unroll
      for (int i=0;i<4;++i)
        pv[nf][i] = on ? exp2_hw(sc[nf][i]) : 0.f;   // Q pre-scaled 0.125*log2e
    }
#pragma unroll
    for (int i=0;i<4;++i){
      const unsigned int lo = pack_bf2(pv[0][i], pv[1][i]);
      const unsigned int hi = pack_bf2(pv[2][i], pv[3][i]);
      *reinterpret_cast<unsigned long long*>(&Pl[w][(quad<<2)+i][l15<<2]) =
          ((unsigned long long)hi<<32) | lo;
    }

    bf8 pa[2];
    pa[0] = *reinterpret_cast<const bf8*>(&Pl[w][l15][quad<<3]);
    pa[1] = *reinterpret_cast<const bf8*>(&Pl[w][l15][32+(quad<<3)]);
    __builtin_amdgcn_s_setprio(1);
    {                                                // lsum on the MFMA pipe
      f32x4 l = MFMA16(pa[0], ones, lsv);
      lsv = MFMA16(pa[1], ones, l);
    }
#pragma unroll
    for (int nf=0;nf<4;++nf){
      const bf8 v0 = *reinterpret_cast<const bf8*>(&VSC[nf*16+l15][quad<<3]);
      const bf8 v1 = *reinterpret_cast<const bf8*>(&VSC[nf*16+l15][32+(quad<<3)]);
      f32x4 o = MFMA16(pa[0], v0, of[nf]);
      of[nf] = MFMA16(pa[1], v1, o);
    }
    __builtin_amdgcn_s_setprio(0);
    __syncthreads();                                 // single barrier per tile
  };

  for (int kt=0; kt<kend; kt+=128){
    iter(Ks[0], Vs[0], Ks[1], Vs[1], kt);
    if (kt + 64 < kend)
      iter(Ks[1], Vs[1], Ks[0], Vs[0], kt+64);
  }

  // scatter valid rows to ORIGINAL positions (Ob pre-zeroed)
  unsigned short* Op = O + (size_t)bh*SEQ*HDIM;
#pragma unroll
  for (int i=0;i<4;++i){
    const int q = qs + (quad<<2) + i;                // compacted q index
    if (q < kcnt){
      const int orig = Idxb[q];
      const float l = lsv[i];
      const float inv = (l > 0.f) ? 1.f/l : 0.f;
#pragma unroll
      for (int nf=0;nf<4;++nf)
        Op[(size_t)orig*HDIM + (nf<<4) + l15] = f2bf(of[nf][i]*inv);
    }
  }
}

// ---------------------------------------------------------------------------
// MFMA GEMM C (chunk-swizzled): out = Ob @ WoutT^T, fp32 stores. 128x64
// tiles, 512 blocks, gload_lds staging. A: f=r&7; B: f=(r>>1)&7 (read rows
// 2*l15+nj -> (row>>1)&7 = l15&7 spreads all 8 positions).
// ---------------------------------------------------------------------------
__global__ __launch_bounds__(256) void gemm_out_mfma(
    const unsigned short* __restrict__ A, const unsigned short* __restrict__ Bt,
    float* __restrict__ Out)
{
  __shared__ unsigned short As[128][64];
  __shared__ unsigned short Bs[64][64];
  const int t = threadIdx.x;
  const int w = t>>6, lane = t&63, quad = lane>>4, l15 = lane&15;
  const int wr = (w>>1)<<6, wc = (w&1)<<5;
  const int linear = blockIdx.y*8 + blockIdx.x;      // grid (8,64) = 512
  const int swz = (linear & 7)*64 + (linear >> 3);   // bijective (512%8==0)
  const int m0 = (swz>>3)<<7, n0 = (swz&7)<<6;
  const int row = t>>3, seg = t&7;
  const int sa = (seg ^ (row & 7)) << 3;             // A source chunk-swizzle
  const int sb = (seg ^ ((row >> 1) & 7)) << 3;      // B source chunk-swizzle
  const unsigned short* Agp = A  + (size_t)(m0+row)*DMODEL + sa;
  const unsigned short* Bgp = Bt + (size_t)(n0+row)*DMODEL + sb;
  f32x4 acc[4][2];
#pragma unroll
  for (int i=0;i<4;++i)
#pragma unroll
    for (int j=0;j<2;++j) acc[i][j] = (f32x4){0.f,0.f,0.f,0.f};

  for (int k0=0;k0<DMODEL;k0+=64){
    __syncthreads();
#pragma unroll
    for (int p=0;p<4;++p)
      gload_lds16(Agp + (size_t)p*32*DMODEL + k0, &As[(w<<3)+(p<<5)][0]);
#pragma unroll
    for (int p=0;p<2;++p)
      gload_lds16(Bgp + (size_t)p*32*DMODEL + k0, &Bs[(w<<3)+(p<<5)][0]);
    __syncthreads();
#pragma unroll
    for (int ks=0;ks<2;++ks){
      const int co = (((ks<<2)|quad) ^ (l15&7)) << 3;  // swizzled read offset
      bf8 af[4], bfr[2];
#pragma unroll
      for (int mi=0;mi<4;++mi)
        af[mi]  = *reinterpret_cast<const bf8*>(&As[wr+mi*16+l15][co]);
#pragma unroll
      for (int nj=0;nj<2;++nj)
        bfr[nj] = *reinterpret_cast<const bf8*>(&Bs[wc+(l15<<1)+nj][co]);
#pragma unroll
      for (int mi=0;mi<4;++mi)
#pragma unroll
        for (int nj=0;nj<2;++nj) acc[mi][nj] = MFMA16(af[mi], bfr[nj], acc[mi][nj]);
    }
  }
  const int cbase = n0 + wc + (l15<<1);
#pragma unroll
  for (int mi=0;mi<4;++mi)
#pragma unroll
    for (int i=0;i<4;++i){
      const int m = m0 + wr + mi*16 + quad*4 + i;
      const float2 o = make_float2(acc[mi][0][i], acc[mi][1][i]);
      *reinterpret_cast<float2*>(Out + (size_t)m*DMODEL + cbase) = o;
    }
}

// ---------------------------------------------------------------------------
extern "C" void kernel_launch(void* const* d_in, const int* in_sizes, int n_in,
                              void* d_out, int out_size, void* d_ws, size_t ws_size,
                              hipStream_t stream) {
  (void)in_sizes; (void)n_in; (void)out_size; (void)ws_size;
  const float* x     = (const float*)d_in[0];
  const int*   pmask = (const int*)d_in[2];
  const float* Wqkv  = (const float*)d_in[3];
  const float* Wout  = (const float*)d_in[4];
  float* out = (float*)d_out;

  const size_t per = (size_t)BATCH*NHEADS*SEQ*HDIM;     // 4,194,304
  unsigned short* Xh    = (unsigned short*)d_ws;
  unsigned short* WqkvT = Xh    + (size_t)8192*512;
  unsigned short* WoutT = WqkvT + (size_t)1536*512;
  unsigned short* QKVb  = WoutT + (size_t)512*512;
  unsigned short* VbT   = QKVb  + (size_t)8192*QKV_N;
  unsigned short* Ob    = VbT + per;
  int* Idx = (int*)(Ob + per);                          // [BATCH][SEQ]
  int* Cnt = Idx + (size_t)BATCH*SEQ;                   // [BATCH]

  prep<<<2820, 256, 0, stream>>>(x, Wqkv, Wout, pmask, Xh, WqkvT, WoutT,
                                 Idx, Cnt, Ob);
  gemm_qkv_mfma<<<dim3(QKV_N/128, 8192/128), 256, 0, stream>>>(Xh, WqkvT, QKVb);
  v_transpose<<<dim3(SEQ/64, BATCH*NHEADS), 256, 0, stream>>>(
      QKVb, Idx, Cnt, VbT);
  attn_mfma<<<dim3(SEQ/128, BATCH*NHEADS), 512, 0, stream>>>(
      QKVb, VbT, Idx, Cnt, Ob);
  gemm_out_mfma<<<dim3(DMODEL/64, 8192/128), 256, 0, stream>>>(Ob, WoutT, out);
}

// Round 15
// 153.132 us; speedup vs baseline: 1.4358x; 1.0007x over previous
//
#include <hip/hip_runtime.h>
#include <hip/hip_bf16.h>
#include <math.h>
#include <stdint.h>

#define BATCH   4
#define SEQ     2048
#define DMODEL  512
#define NHEADS  8
#define HDIM    64
#define QKV_N   (3*DMODEL)   // 1536

typedef short bf8  __attribute__((ext_vector_type(8)));   // 8 bf16 (4 VGPRs)
typedef float f32x4 __attribute__((ext_vector_type(4)));  // 4 fp32 acc

#define MFMA16(a,b,c) __builtin_amdgcn_mfma_f32_16x16x32_bf16((a),(b),(c),0,0,0)

__device__ inline unsigned short f2bf(float f){      // RNE fp32->bf16
  unsigned int u = __float_as_uint(f);
  u += 0x7FFFu + ((u >> 16) & 1u);
  return (unsigned short)(u >> 16);
}

__device__ inline unsigned int pack_bf2(float a, float b){  // v_cvt_pk_bf16_f32
  __hip_bfloat162 h = __float22bfloat162_rn(make_float2(a, b));
  return *reinterpret_cast<unsigned int*>(&h);
}

// raw v_exp_f32: computes 2^x (Q is pre-scaled by 0.125*log2(e) upstream)
__device__ __forceinline__ float exp2_hw(float x){
#if defined(__has_builtin)
#if __has_builtin(__builtin_amdgcn_exp2f)
  return __builtin_amdgcn_exp2f(x);
#else
  float r; asm("v_exp_f32 %0, %1" : "=v"(r) : "v"(x)); return r;
#endif
#else
  float r; asm("v_exp_f32 %0, %1" : "=v"(r) : "v"(x)); return r;
#endif
}

// global -> LDS direct DMA, 16 B per lane. LDS dest = wave-uniform base +
// lane*16 (LDS stays LINEAR; swizzles are applied on the per-lane GLOBAL
// source address + matching read offset — rule #21 both-sides involution).
__device__ __forceinline__ void gload_lds16(const unsigned short* g,
                                            unsigned short* l){
  __builtin_amdgcn_global_load_lds(
      (const __attribute__((address_space(1))) unsigned int*)g,
      (__attribute__((address_space(3))) unsigned int*)l,
      16, 0, 0);
}

// ---------------------------------------------------------------------------
// Fused prepass: cast x -> bf16 (0..2047), transpose+cast W_qkv (2048..2239),
// transpose+cast W_out (2240..2303), per-batch valid-position compaction scan
// in VIRTUAL space (2304..2307), zero Ob (2308..2819).
// ---------------------------------------------------------------------------
__global__ __launch_bounds__(256) void prep(
    const float* __restrict__ x, const float* __restrict__ Wqkv,
    const float* __restrict__ Wout, const int* __restrict__ pmask,
    unsigned short* __restrict__ Xh, unsigned short* __restrict__ WqkvT,
    unsigned short* __restrict__ WoutT, int* __restrict__ Idx,
    int* __restrict__ Cnt, unsigned short* __restrict__ Ob)
{
  __shared__ unsigned short Ts[64][72];
  __shared__ int ps[256];
  __shared__ int tot;
  const int t = threadIdx.x;
  const int bx = blockIdx.x;
  if (bx < 2048) {
    const int i = bx*256 + t;
    const float4 a = reinterpret_cast<const float4*>(x)[2*i];
    const float4 b = reinterpret_cast<const float4*>(x)[2*i+1];
    uint4 o; unsigned short* us = reinterpret_cast<unsigned short*>(&o);
    us[0]=f2bf(a.x); us[1]=f2bf(a.y); us[2]=f2bf(a.z); us[3]=f2bf(a.w);
    us[4]=f2bf(b.x); us[5]=f2bf(b.y); us[6]=f2bf(b.z); us[7]=f2bf(b.w);
    reinterpret_cast<uint4*>(Xh)[i] = o;
    return;
  }
  if (bx >= 2308) {                                  // zero Ob (8 MB)
    const int g = (bx - 2308)*256 + t;
    uint4 z = {0u,0u,0u,0u};
    uint4* p = reinterpret_cast<uint4*>(Ob) + (size_t)g*4;
    p[0]=z; p[1]=z; p[2]=z; p[3]=z;
    return;
  }
  if (bx >= 2304) {                                  // mask compaction scan
    const int b = bx - 2304;
    const int* mb = pmask + b*SEQ;
    int loc[8]; int c = 0; const int base = t*8;
#pragma unroll
    for (int j=0;j<8;++j){ const int v = (mb[base+j] != 0); loc[j]=v; c+=v; }
    ps[t] = c; __syncthreads();
    for (int off=1; off<256; off<<=1){               // Hillis-Steele inclusive
      const int v = (t>=off) ? ps[t-off] : 0;
      __syncthreads(); ps[t] += v; __syncthreads();
    }
    int excl = ps[t] - c;
#pragma unroll
    for (int j=0;j<8;++j) if (loc[j]) Idx[b*SEQ + (excl++)] = base + j;
    if (t == 255){ Cnt[b] = ps[255]; tot = ps[255]; }
    __syncthreads();
    for (int k = tot + t; k < SEQ; k += 256) Idx[b*SEQ + k] = 0;
    return;
  }
  const float* in; unsigned short* out; int R, C, gx, gy;
  if (bx < 2048 + 192) {
    const int bid = bx - 2048;
    gx = bid % 24; gy = bid / 24; in = Wqkv; out = WqkvT; R = DMODEL; C = QKV_N;
  } else {
    const int bid = bx - 2240;
    gx = bid % 8;  gy = bid / 8;  in = Wout; out = WoutT; R = DMODEL; C = DMODEL;
  }
  const int r0 = gy<<6, c0 = gx<<6;
  const int rr = t>>2, cs = (t&3)<<4;
#pragma unroll
  for (int p=0;p<4;++p){
    float4 v = *reinterpret_cast<const float4*>(in + (size_t)(r0+rr)*C + c0 + cs + p*4);
    Ts[rr][cs+p*4+0]=f2bf(v.x); Ts[rr][cs+p*4+1]=f2bf(v.y);
    Ts[rr][cs+p*4+2]=f2bf(v.z); Ts[rr][cs+p*4+3]=f2bf(v.w);
  }
  __syncthreads();
  const int cc = t>>2, rs = (t&3)<<4;
#pragma unroll
  for (int p=0;p<4;++p){
    ushort4 o;
    o.x = Ts[rs+p*4+0][cc]; o.y = Ts[rs+p*4+1][cc];
    o.z = Ts[rs+p*4+2][cc]; o.w = Ts[rs+p*4+3][cc];
    *reinterpret_cast<ushort4*>(out + (size_t)(c0+cc)*R + r0 + rs + p*4) = o;
  }
}

// ---------------------------------------------------------------------------
// MFMA GEMM A v3: chunk-swizzled + LDS-double-buffered gload_lds pipeline.
// Per K-step: issue loads(k+1)->buf[cur^1] FIRST, compute buf[cur] (~300cy
// of ds_read+MFMA covers the load latency), ONE barrier (drains vmcnt ->
// k+1 landed; cur reads done). Was: issue-then-drain with zero overlap.
// Zero VGPR cost (round-12's reg-prefetch spilled). LDS 64 KB -> 2 blk/CU.
// ---------------------------------------------------------------------------
__global__ __launch_bounds__(256) void gemm_qkv_mfma(
    const unsigned short* __restrict__ A, const unsigned short* __restrict__ Bt,
    unsigned short* __restrict__ QKV)
{
  __shared__ unsigned short As[2][128][64];
  __shared__ unsigned short Bs[2][128][64];
  const int t = threadIdx.x;
  const int w = t>>6, lane = t&63, quad = lane>>4, l15 = lane&15;
  const int wr = (w>>1)<<6, wc = (w&1)<<6;
  const int linear = blockIdx.y*12 + blockIdx.x;     // 768 blocks
  const int swz = (linear & 7)*96 + (linear >> 3);   // bijective (768%8==0)
  const int m0 = (swz/12)<<7, n0 = (swz%12)<<7;
  const int row = t>>3, seg = t&7;
  const int sa = (seg ^ (row & 7)) << 3;             // A source chunk-swizzle
  const int sb = (seg ^ ((row >> 2) & 7)) << 3;      // B source chunk-swizzle
  const unsigned short* Agp = A  + (size_t)(m0+row)*DMODEL + sa;
  const unsigned short* Bgp = Bt + (size_t)(n0+row)*DMODEL + sb;
  f32x4 acc[4][4];
#pragma unroll
  for (int i=0;i<4;++i)
#pragma unroll
    for (int j=0;j<4;++j) acc[i][j] = (f32x4){0.f,0.f,0.f,0.f};

  // prologue: stage k0=0 into buf 0
#pragma unroll
  for (int p=0;p<4;++p){
    gload_lds16(Agp + (size_t)p*32*DMODEL, &As[0][(w<<3)+(p<<5)][0]);
    gload_lds16(Bgp + (size_t)p*32*DMODEL, &Bs[0][(w<<3)+(p<<5)][0]);
  }
  __syncthreads();                                   // buf0 ready

#pragma unroll
  for (int kk=0; kk<DMODEL/64; ++kk){
    const int cur = kk & 1;
    if (kk + 1 < DMODEL/64){                         // loads for k+1 in flight
#pragma unroll
      for (int p=0;p<4;++p){
        gload_lds16(Agp + (size_t)p*32*DMODEL + (kk+1)*64,
                    &As[cur^1][(w<<3)+(p<<5)][0]);
        gload_lds16(Bgp + (size_t)p*32*DMODEL + (kk+1)*64,
                    &Bs[cur^1][(w<<3)+(p<<5)][0]);
      }
    }
#pragma unroll
    for (int ks=0;ks<2;++ks){
      const int co = (((ks<<2)|quad) ^ (l15&7)) << 3;  // swizzled read offset
      bf8 af[4], bfr[4];
#pragma unroll
      for (int mi=0;mi<4;++mi)
        af[mi]  = *reinterpret_cast<const bf8*>(&As[cur][wr+mi*16+l15][co]);
#pragma unroll
      for (int nj=0;nj<4;++nj)
        bfr[nj] = *reinterpret_cast<const bf8*>(&Bs[cur][wc+(l15<<2)+nj][co]);
#pragma unroll
      for (int mi=0;mi<4;++mi)
#pragma unroll
        for (int nj=0;nj<4;++nj) acc[mi][nj] = MFMA16(af[mi], bfr[nj], acc[mi][nj]);
    }
    __syncthreads();                                 // k+1 landed; cur reads done
  }
  const int cbase = n0 + wc + (l15<<2);
  bool isq[4];
#pragma unroll
  for (int nj=0;nj<4;++nj) isq[nj] = ((cbase+nj) % 192) < 64;
#pragma unroll
  for (int mi=0;mi<4;++mi)
#pragma unroll
    for (int i=0;i<4;++i){
      const int m = m0 + wr + mi*16 + quad*4 + i;
      unsigned long long pk = 0;
#pragma unroll
      for (int nj=0;nj<4;++nj){
        float v = acc[mi][nj][i];
        if (isq[nj]) v *= 0.18033688f;               // 0.125 * log2(e)
        pk |= (unsigned long long)f2bf(v) << (16*nj);
      }
      *reinterpret_cast<unsigned long long*>(QKV + (size_t)m*QKV_N + cbase) = pk;
    }
}

// ---------------------------------------------------------------------------
// V^T builder (compacted in VIRTUAL space): VT[bh][d][j] = V of virtual
// position Idx[b][j]. Tiles beyond ceil64(cnt[b]) exit (never read).
// ---------------------------------------------------------------------------
__global__ __launch_bounds__(256) void v_transpose(
    const unsigned short* __restrict__ QKV, const int* __restrict__ Idx,
    const int* __restrict__ Cnt, unsigned short* __restrict__ VT)
{
  __shared__ unsigned short Td[64][76];
  const int t = threadIdx.x;
  const int bh = blockIdx.y, b = bh>>3, hp = bh&7;
  const int s0 = blockIdx.x<<6;
  if (s0 >= ((Cnt[b] + 63) & ~63)) return;           // dead tile
  const size_t rbase = (size_t)(b*SEQ + hp*256);
  const int sr = t>>2, db = (t&3)<<4;
  const int s = Idx[b*SEQ + s0 + sr];                // gather source key
  const unsigned short* vp =
      QKV + (rbase + (s>>3))*QKV_N + (s&7)*192 + 128 + db;
  uint4 a = *reinterpret_cast<const uint4*>(vp);
  uint4 c = *reinterpret_cast<const uint4*>(vp + 8);
  const unsigned short* ua = reinterpret_cast<const unsigned short*>(&a);
  const unsigned short* uc = reinterpret_cast<const unsigned short*>(&c);
#pragma unroll
  for (int j=0;j<8;++j) Td[db+j][sr]   = ua[j];
#pragma unroll
  for (int j=0;j<8;++j) Td[db+8+j][sr] = uc[j];
  __syncthreads();
  const int L = t&15, d0 = t>>4;
  unsigned short* Op = VT + (size_t)bh*HDIM*SEQ + s0 + (L<<2);
#pragma unroll
  for (int cc=0;cc<4;++cc){
    const int d = d0 + (cc<<4);
    *reinterpret_cast<unsigned long long*>(Op + (size_t)d*SEQ) =
        *reinterpret_cast<const unsigned long long*>(&Td[d][L<<2]);
  }
}

// ---------------------------------------------------------------------------
// MFMA flash attention v14: q-compaction on the 8-wave 128q/block geometry.
// Q/K gathered via Idx; VT pre-compacted; tail key mask (pos < cnt);
// epilogue scatters to ORIGINAL positions (Ob pre-zeroed).
// ---------------------------------------------------------------------------
__global__ __launch_bounds__(512, 4) void attn_mfma(
    const unsigned short* __restrict__ QKV, const unsigned short* __restrict__ VT,
    const int* __restrict__ Idx, const int* __restrict__ Cnt,
    unsigned short* __restrict__ O)
{
  __shared__ unsigned short Ks[2][64][72];   // rho-permuted K tiles [row][d]
  __shared__ unsigned short Vs[2][64][72];   // V^T tiles [d][key]
  __shared__ unsigned short Pl[8][16][72];   // wave-private P [q][key]
  const int t = threadIdx.x;
  const int w = t>>6, lane = t&63, quad = lane>>4, l15 = lane&15;
  const int linear = blockIdx.y*16 + blockIdx.x;     // 512 blocks
  const int swz = (linear & 7)*64 + (linear >> 3);   // bijective (512%8==0)
  const int bh = swz >> 4, b = bh>>3, hp = bh&7;
  const int q0 = (swz & 15) << 7;            // 128 queries per block
  const int kcnt = Cnt[b];
  const int kend = (kcnt + 63) & ~63;                // compacted tile span
  if (q0 >= kend) return;                            // dead q-tile (block-uniform)
  const int qs = q0 + (w<<4);                // 16 per wave
  const int* Idxb = Idx + b*SEQ;
  const f32x4 Z4 = {0.f,0.f,0.f,0.f};

  const size_t rbase = (size_t)(b*SEQ + hp*256);   // qkv row base for this bh
  bf8 qf[2];
  {
    const int sq = Idxb[qs + l15];                   // virtual-space gather
    const unsigned short* qp =
        QKV + (rbase + (sq>>3))*QKV_N + (sq&7)*192 + (quad<<3);
    qf[0] = *reinterpret_cast<const bf8*>(qp);
    qf[1] = *reinterpret_cast<const bf8*>(qp + 32);
  }
  const unsigned short* Vg = VT + (size_t)bh*HDIM*SEQ;

  bf8 ones;
#pragma unroll
  for (int j=0;j<8;++j) ones[j] = (short)0x3F80;    // bf16 1.0

  const int srow = t>>3, sc8 = (t&7)<<3;             // staging: key row, col
  const int krow = ((srow&3)<<4) + (srow>>2);        // rho(srow)

  f32x4 of[4]; f32x4 lsv = Z4;
#pragma unroll
  for (int i=0;i<4;++i) of[i]=Z4;

  uint4 gk0, gv0;
  {                                                  // load tile 0 (gathered)
    const int s = Idxb[srow];
    const unsigned short* kp =
        QKV + (rbase + (s>>3))*QKV_N + (s&7)*192 + 64 + sc8;
    gk0 = *reinterpret_cast<const uint4*>(kp);
    gv0 = *reinterpret_cast<const uint4*>(Vg + (size_t)srow*SEQ + sc8);
  }
  // write buf0 (waits on tile-0 loads), then issue tile-1 loads
  *reinterpret_cast<uint4*>(&Ks[0][krow][sc8]) = gk0;
  *reinterpret_cast<uint4*>(&Vs[0][srow][sc8]) = gv0;
  {
    const int s = Idxb[64 + srow];
    const unsigned short* kp =
        QKV + (rbase + (s>>3))*QKV_N + (s&7)*192 + 64 + sc8;
    gk0 = *reinterpret_cast<const uint4*>(kp);
    gv0 = *reinterpret_cast<const uint4*>(Vg + (size_t)srow*SEQ + 64 + sc8);
  }
  __syncthreads();                                   // buf0 visible

  auto iter = [&](unsigned short (&KSC)[64][72], unsigned short (&VSC)[64][72],
                  unsigned short (&KSN)[64][72], unsigned short (&VSN)[64][72],
                  int kt) {
    if (kt + 64 < kend){                             // stage tile t+1 -> NXT
      *reinterpret_cast<uint4*>(&KSN[krow][sc8]) = gk0;
      *reinterpret_cast<uint4*>(&VSN[srow][sc8]) = gv0;
    }
    if (kt + 128 < kend){                            // issue loads tile t+2
      const int s = Idxb[kt + 128 + srow];
      const unsigned short* kp =
          QKV + (rbase + (s>>3))*QKV_N + (s&7)*192 + 64 + sc8;
      gk0 = *reinterpret_cast<const uint4*>(kp);
      gv0 = *reinterpret_cast<const uint4*>(
          Vg + (size_t)srow*SEQ + (kt + 128) + sc8);
    }

    bf8 kf[4][2];
#pragma unroll
    for (int nf=0;nf<4;++nf){
      kf[nf][0] = *reinterpret_cast<const bf8*>(&KSC[nf*16+l15][quad<<3]);
      kf[nf][1] = *reinterpret_cast<const bf8*>(&KSC[nf*16+l15][32+(quad<<3)]);
    }

    f32x4 sc[4];
    __builtin_amdgcn_s_setprio(1);
#pragma unroll
    for (int nf=0;nf<4;++nf){
      f32x4 s = MFMA16(qf[0], kf[nf][0], Z4);
      sc[nf] = MFMA16(qf[1], kf[nf][1], s);
    }
    __builtin_amdgcn_s_setprio(0);
    const int kbase = kt + (l15<<2);
    float pv[4][4];
#pragma unroll
    for (int nf=0;nf<4;++nf){
      const bool on = (kbase + nf) < kcnt;           // tail-tile mask only
#pragma unroll
      for (int i=0;i<4;++i)
        pv[nf][i] = on ? exp2_hw(sc[nf][i]) : 0.f;   // Q pre-scaled 0.125*log2e
    }
#pragma unroll
    for (int i=0;i<4;++i){
      const unsigned int lo = pack_bf2(pv[0][i], pv[1][i]);
      const unsigned int hi = pack_bf2(pv[2][i], pv[3][i]);
      *reinterpret_cast<unsigned long long*>(&Pl[w][(quad<<2)+i][l15<<2]) =
          ((unsigned long long)hi<<32) | lo;
    }

    bf8 pa[2];
    pa[0] = *reinterpret_cast<const bf8*>(&Pl[w][l15][quad<<3]);
    pa[1] = *reinterpret_cast<const bf8*>(&Pl[w][l15][32+(quad<<3)]);
    __builtin_amdgcn_s_setprio(1);
    {                                                // lsum on the MFMA pipe
      f32x4 l = MFMA16(pa[0], ones, lsv);
      lsv = MFMA16(pa[1], ones, l);
    }
#pragma unroll
    for (int nf=0;nf<4;++nf){
      const bf8 v0 = *reinterpret_cast<const bf8*>(&VSC[nf*16+l15][quad<<3]);
      const bf8 v1 = *reinterpret_cast<const bf8*>(&VSC[nf*16+l15][32+(quad<<3)]);
      f32x4 o = MFMA16(pa[0], v0, of[nf]);
      of[nf] = MFMA16(pa[1], v1, o);
    }
    __builtin_amdgcn_s_setprio(0);
    __syncthreads();                                 // single barrier per tile
  };

  for (int kt=0; kt<kend; kt+=128){
    iter(Ks[0], Vs[0], Ks[1], Vs[1], kt);
    if (kt + 64 < kend)
      iter(Ks[1], Vs[1], Ks[0], Vs[0], kt+64);
  }

  // scatter valid rows to ORIGINAL positions (Ob pre-zeroed)
  unsigned short* Op = O + (size_t)bh*SEQ*HDIM;
#pragma unroll
  for (int i=0;i<4;++i){
    const int q = qs + (quad<<2) + i;                // compacted q index
    if (q < kcnt){
      const int orig = Idxb[q];
      const float l = lsv[i];
      const float inv = (l > 0.f) ? 1.f/l : 0.f;
#pragma unroll
      for (int nf=0;nf<4;++nf)
        Op[(size_t)orig*HDIM + (nf<<4) + l15] = f2bf(of[nf][i]*inv);
    }
  }
}

// ---------------------------------------------------------------------------
// MFMA GEMM C v3: chunk-swizzled + LDS-double-buffered gload_lds pipeline
// (same transform as gemm_qkv). LDS 48 KB -> 3 blocks/CU.
// ---------------------------------------------------------------------------
__global__ __launch_bounds__(256) void gemm_out_mfma(
    const unsigned short* __restrict__ A, const unsigned short* __restrict__ Bt,
    float* __restrict__ Out)
{
  __shared__ unsigned short As[2][128][64];
  __shared__ unsigned short Bs[2][64][64];
  const int t = threadIdx.x;
  const int w = t>>6, lane = t&63, quad = lane>>4, l15 = lane&15;
  const int wr = (w>>1)<<6, wc = (w&1)<<5;
  const int linear = blockIdx.y*8 + blockIdx.x;      // grid (8,64) = 512
  const int swz = (linear & 7)*64 + (linear >> 3);   // bijective (512%8==0)
  const int m0 = (swz>>3)<<7, n0 = (swz&7)<<6;
  const int row = t>>3, seg = t&7;
  const int sa = (seg ^ (row & 7)) << 3;             // A source chunk-swizzle
  const int sb = (seg ^ ((row >> 1) & 7)) << 3;      // B source chunk-swizzle
  const unsigned short* Agp = A  + (size_t)(m0+row)*DMODEL + sa;
  const unsigned short* Bgp = Bt + (size_t)(n0+row)*DMODEL + sb;
  f32x4 acc[4][2];
#pragma unroll
  for (int i=0;i<4;++i)
#pragma unroll
    for (int j=0;j<2;++j) acc[i][j] = (f32x4){0.f,0.f,0.f,0.f};

  // prologue: stage k0=0 into buf 0
#pragma unroll
  for (int p=0;p<4;++p)
    gload_lds16(Agp + (size_t)p*32*DMODEL, &As[0][(w<<3)+(p<<5)][0]);
#pragma unroll
  for (int p=0;p<2;++p)
    gload_lds16(Bgp + (size_t)p*32*DMODEL, &Bs[0][(w<<3)+(p<<5)][0]);
  __syncthreads();                                   // buf0 ready

#pragma unroll
  for (int kk=0; kk<DMODEL/64; ++kk){
    const int cur = kk & 1;
    if (kk + 1 < DMODEL/64){                         // loads for k+1 in flight
#pragma unroll
      for (int p=0;p<4;++p)
        gload_lds16(Agp + (size_t)p*32*DMODEL + (kk+1)*64,
                    &As[cur^1][(w<<3)+(p<<5)][0]);
#pragma unroll
      for (int p=0;p<2;++p)
        gload_lds16(Bgp + (size_t)p*32*DMODEL + (kk+1)*64,
                    &Bs[cur^1][(w<<3)+(p<<5)][0]);
    }
#pragma unroll
    for (int ks=0;ks<2;++ks){
      const int co = (((ks<<2)|quad) ^ (l15&7)) << 3;  // swizzled read offset
      bf8 af[4], bfr[2];
#pragma unroll
      for (int mi=0;mi<4;++mi)
        af[mi]  = *reinterpret_cast<const bf8*>(&As[cur][wr+mi*16+l15][co]);
#pragma unroll
      for (int nj=0;nj<2;++nj)
        bfr[nj] = *reinterpret_cast<const bf8*>(&Bs[cur][wc+(l15<<1)+nj][co]);
#pragma unroll
      for (int mi=0;mi<4;++mi)
#pragma unroll
        for (int nj=0;nj<2;++nj) acc[mi][nj] = MFMA16(af[mi], bfr[nj], acc[mi][nj]);
    }
    __syncthreads();                                 // k+1 landed; cur reads done
  }
  const int cbase = n0 + wc + (l15<<1);
#pragma unroll
  for (int mi=0;mi<4;++mi)
#pragma unroll
    for (int i=0;i<4;++i){
      const int m = m0 + wr + mi*16 + quad*4 + i;
      const float2 o = make_float2(acc[mi][0][i], acc[mi][1][i]);
      *reinterpret_cast<float2*>(Out + (size_t)m*DMODEL + cbase) = o;
    }
}

// ---------------------------------------------------------------------------
extern "C" void kernel_launch(void* const* d_in, const int* in_sizes, int n_in,
                              void* d_out, int out_size, void* d_ws, size_t ws_size,
                              hipStream_t stream) {
  (void)in_sizes; (void)n_in; (void)out_size; (void)ws_size;
  const float* x     = (const float*)d_in[0];
  const int*   pmask = (const int*)d_in[2];
  const float* Wqkv  = (const float*)d_in[3];
  const float* Wout  = (const float*)d_in[4];
  float* out = (float*)d_out;

  const size_t per = (size_t)BATCH*NHEADS*SEQ*HDIM;     // 4,194,304
  unsigned short* Xh    = (unsigned short*)d_ws;
  unsigned short* WqkvT = Xh    + (size_t)8192*512;
  unsigned short* WoutT = WqkvT + (size_t)1536*512;
  unsigned short* QKVb  = WoutT + (size_t)512*512;
  unsigned short* VbT   = QKVb  + (size_t)8192*QKV_N;
  unsigned short* Ob    = VbT + per;
  int* Idx = (int*)(Ob + per);                          // [BATCH][SEQ]
  int* Cnt = Idx + (size_t)BATCH*SEQ;                   // [BATCH]

  prep<<<2820, 256, 0, stream>>>(x, Wqkv, Wout, pmask, Xh, WqkvT, WoutT,
                                 Idx, Cnt, Ob);
  gemm_qkv_mfma<<<dim3(QKV_N/128, 8192/128), 256, 0, stream>>>(Xh, WqkvT, QKVb);
  v_transpose<<<dim3(SEQ/64, BATCH*NHEADS), 256, 0, stream>>>(
      QKVb, Idx, Cnt, VbT);
  attn_mfma<<<dim3(SEQ/128, BATCH*NHEADS), 512, 0, stream>>>(
      QKVb, VbT, Idx, Cnt, Ob);
  gemm_out_mfma<<<dim3(DMODEL/64, 8192/128), 256, 0, stream>>>(Ob, WoutT, out);
}